// Round 2
// baseline (170.470 us; speedup 1.0000x reference)
//
#include <hip/hip_runtime.h>
#include <hip/hip_bf16.h>
#include <math.h>

#define BATCH 4096
#define DIM   2048
#define INV_T 2.0f   // 1 / TEMPERATURE, TEMPERATURE = 0.5

#define BM 256
#define BN 256

typedef float floatx4 __attribute__((ext_vector_type(4)));
typedef int   intx4   __attribute__((ext_vector_type(4)));
typedef int   intx8   __attribute__((ext_vector_type(8)));

static __device__ __forceinline__ void gld_lds16(const void* g, void* l) {
  __builtin_amdgcn_global_load_lds(
      (const __attribute__((address_space(1))) void*)g,
      (__attribute__((address_space(3))) void*)l, 16, 0, 0);
}

static __device__ __forceinline__ intx8 comb8(intx4 lo, intx4 hi) {
  intx8 r;
  r[0] = lo[0]; r[1] = lo[1]; r[2] = lo[2]; r[3] = lo[3];
  r[4] = hi[0]; r[5] = hi[1]; r[6] = hi[2]; r[7] = hi[3];
  return r;
}

// ---------------------------------------------------------------------------
// Kernel 1: per-row log-softmax prep. Wave-per-row, NO barriers. (unchanged)
//   rows [0, B)  -> Li8 = fp8_e4m3(log_softmax(c_i))
//   rows [B, 2B) -> Qb8 = fp8_e4m3(softmax(c_j) * 2^t_j)  (per-row pow2 scale
//                   so max lands ~[128,256): avoids e4m3 underflow)
//                   + hneg fp32 (from EXACT fp32 Q) + isc = 2^-t + rowsum = 0
// ---------------------------------------------------------------------------
__global__ __launch_bounds__(256) void prep_kernel(
    const float* __restrict__ ci, const float* __restrict__ cj,
    unsigned char* __restrict__ Li8, unsigned char* __restrict__ Qb8,
    float* __restrict__ hneg, float* __restrict__ isc,
    float* __restrict__ rowsum, float* __restrict__ out)
{
  const int lane = threadIdx.x & 63;
  const int wave = threadIdx.x >> 6;
  const int row = blockIdx.x * 4 + wave;
  const bool isj = row >= BATCH;
  const int r = isj ? row - BATCH : row;
  const float* __restrict__ src = (isj ? cj : ci) + (size_t)r * DIM;

  // 32 elements per lane: float4 chunks at [i*64 + lane], i = 0..7
  float v[32];
  #pragma unroll
  for (int i = 0; i < 8; ++i) {
    float4 t = ((const float4*)src)[i * 64 + lane];
    v[i * 4 + 0] = t.x; v[i * 4 + 1] = t.y;
    v[i * 4 + 2] = t.z; v[i * 4 + 3] = t.w;
  }

  // wave max
  float m = v[0];
  #pragma unroll
  for (int i = 1; i < 32; ++i) m = fmaxf(m, v[i]);
  #pragma unroll
  for (int off = 32; off >= 1; off >>= 1) m = fmaxf(m, __shfl_xor(m, off));

  // wave sum of exp(v - m)
  float s = 0.f;
  #pragma unroll
  for (int i = 0; i < 32; ++i) s += __expf(v[i] - m);
  #pragma unroll
  for (int off = 32; off >= 1; off >>= 1) s += __shfl_xor(s, off);
  const float ls = m + __logf(s);          // logsumexp of row

  // per-row pow2 scale for Q rows: Qmax = exp(m - ls); want Qmax*2^t in [128,256)
  float scale = 1.f;
  int t = 0;
  if (isj) {
    const float qmax = __expf(m - ls);
    const int be = (int)((__float_as_uint(qmax) >> 23) & 0xff);
    t = 134 - be;                          // qmax*2^t in [128,256)
    scale = __uint_as_float((unsigned)(t + 127) << 23);
  }

  unsigned char* dst = (isj ? Qb8 : Li8) + (size_t)r * DIM;
  float h = 0.f;
  #pragma unroll
  for (int i = 0; i < 8; ++i) {
    float f[4];
    #pragma unroll
    for (int j = 0; j < 4; ++j) {
      const float li = v[i * 4 + j] - ls;  // log_softmax element
      if (isj) {
        const float q = __expf(li);        // exact softmax element
        h += q * li;                       // negative entropy (fp32, exact Q)
        f[j] = q * scale;
      } else {
        f[j] = li;
      }
    }
    int w = __builtin_amdgcn_cvt_pk_fp8_f32(f[0], f[1], 0, false);
    w = __builtin_amdgcn_cvt_pk_fp8_f32(f[2], f[3], w, true);
    ((int*)dst)[i * 64 + lane] = w;        // bytes (i*256 + lane*4) ..+3
  }

  if (isj) {
    #pragma unroll
    for (int off = 32; off >= 1; off >>= 1) h += __shfl_xor(h, off);
    if (lane == 0) {
      hneg[r] = h;
      isc[r] = __uint_as_float((unsigned)(127 - t) << 23);  // 2^-t
      rowsum[r] = 0.f;
    }
  }
  if (row == 0 && lane == 0) out[0] = 0.f;
}

// ---------------------------------------------------------------------------
// Kernel 2 (R7): cross' = Li8 @ Qb8^T via MX-fp8 MFMA (16x16x128, scale=1.0).
// 256^2 tile, 8-wave 4-phase counted-vmcnt schedule (T1+T3+T4+T5).
// R7 fix vs R6: __launch_bounds__(512, 1). R6's (512,2) pinned regalloc to
// the 4-waves/EU class (<=128 arch VGPR) while the schedule needs ~210
// (acc 128 + bf 32 + af 16 + addressing) -> main-loop scratch spill,
// WRITE_SIZE 6 MB -> 200 MB, MfmaUtil 16%. LDS (128 KB) limits occupancy
// to 1 block/CU regardless, so (512,1) costs nothing and un-spills.
// ---------------------------------------------------------------------------
__global__ __launch_bounds__(512, 1) void gemm_lse_kernel(
    const unsigned char* __restrict__ Li8, const unsigned char* __restrict__ Qb8,
    const float* __restrict__ hneg, const float* __restrict__ isc,
    float* __restrict__ rowsum, float* __restrict__ diag)
{
  // 2 dbuf x (A 256x128 + B 256x128) fp8 = 128 KB
  __shared__ __attribute__((aligned(16))) unsigned char As_[2][BM * 128];
  __shared__ __attribute__((aligned(16))) unsigned char Bs_[2][BN * 128];

  const int tid  = threadIdx.x;
  // XCD-aware patch mapping: 256 blocks, xcd = lin&7 owns a 4(by) x 8(bx)
  // rectangle of the 16x16 tile grid (bijective).
  const int lin = blockIdx.x;
  const int xc  = lin & 7;
  const int sq  = lin >> 3;                // 0..31
  const int by  = (xc & 3) * 4 + (sq & 3);
  const int bx  = (xc >> 2) * 8 + (sq >> 2);

  const int lane = tid & 63;
  const int wave = tid >> 6;               // 0..7
  const int wm   = wave >> 2;              // 0..1 -> row band wm*128
  const int wn   = wave & 3;               // 0..3 -> col band wn*64

  // staging: 2048 16B-chunks per operand-tile; thread t does chunks t+512*s.
  // LDS chunk p holds global chunk (row = p>>3, cb = (p&7) ^ (row&7)).
  int soff[4];
  #pragma unroll
  for (int s = 0; s < 4; ++s) {
    const int p = tid + 512 * s;
    const int row = p >> 3;
    const int cbg = (p & 7) ^ (row & 7);
    soff[s] = row * DIM + cbg * 16;
  }
  const unsigned char* Abase = Li8 + (size_t)(by * BM) * DIM;
  const unsigned char* Bbase = Qb8 + (size_t)(bx * BN) * DIM;

  const int rl = lane & 15;                // m/n within frag; col within C/D
  const int q  = lane >> 4;                // k-quad: k in [q*32, q*32+32)
  const int sw = rl & 7;                   // XOR swizzle key (row & 7)

  floatx4 acc[8][4];
  const floatx4 z = {0.f, 0.f, 0.f, 0.f};
  #pragma unroll
  for (int mt = 0; mt < 8; ++mt)
    #pragma unroll
    for (int nt = 0; nt < 4; ++nt) acc[mt][nt] = z;

  // prologue: stage K-tile 0 into buffer 0 (8 loads/thread)
  #pragma unroll
  for (int s = 0; s < 4; ++s) {
    gld_lds16(Abase + soff[s], &As_[0][0] + (tid + 512 * s) * 16);
    gld_lds16(Bbase + soff[s], &Bs_[0][0] + (tid + 512 * s) * 16);
  }

  for (int t = 0; t < 16; ++t) {
    const unsigned char* Ab = &As_[t & 1][0];
    const unsigned char* Bb = &Bs_[t & 1][0];
    unsigned char* An = &As_[(t & 1) ^ 1][0];
    unsigned char* Bn = &Bs_[(t & 1) ^ 1][0];
    const int kn = (t + 1) * 128;
    const bool pf = (t < 15);

    intx8 bf[4];

    #pragma unroll
    for (int p = 0; p < 4; ++p) {
      if (p == 0) {
        // boundary: issue first staging pair for t+1, then counted wait for
        // ALL of tile t's loads (2 newest stay in flight), then barrier so
        // every wave's staging of tile t is known-landed chip-wide.
        if (pf) {
          gld_lds16(Abase + soff[0] + kn, An + tid * 16);
          gld_lds16(Bbase + soff[0] + kn, Bn + tid * 16);
          asm volatile("s_waitcnt vmcnt(2)" ::: "memory");
        } else {
          asm volatile("s_waitcnt vmcnt(0)" ::: "memory");
        }
        asm volatile("s_barrier" ::: "memory");
        // B fragments for the whole K-tile (held across phases, 32 VGPRs)
        #pragma unroll
        for (int nt = 0; nt < 4; ++nt) {
          const int rb = wn * 64 + nt * 16 + rl;
          const int q0 = rb * 8 + ((2 * q) ^ sw);
          const int q1 = rb * 8 + ((2 * q + 1) ^ sw);
          bf[nt] = comb8(*(const intx4*)(Bb + q0 * 16),
                         *(const intx4*)(Bb + q1 * 16));
        }
      }
      // A fragments for this phase's mt pair (issued before the barrier for
      // phases 1-3 so the ds_read latency hides under other waves' MFMA)
      intx8 af0, af1;
      {
        const int ra0 = wm * 128 + (2 * p) * 16 + rl;
        const int a00 = ra0 * 8 + ((2 * q) ^ sw);
        const int a01 = ra0 * 8 + ((2 * q + 1) ^ sw);
        af0 = comb8(*(const intx4*)(Ab + a00 * 16),
                    *(const intx4*)(Ab + a01 * 16));
        const int ra1 = wm * 128 + (2 * p + 1) * 16 + rl;
        const int a10 = ra1 * 8 + ((2 * q) ^ sw);
        const int a11 = ra1 * 8 + ((2 * q + 1) ^ sw);
        af1 = comb8(*(const intx4*)(Ab + a10 * 16),
                    *(const intx4*)(Ab + a11 * 16));
      }
      if (p != 0) {
        // spread staging: one A/B pair per phase (keeps loads in flight
        // across barriers; max ~10 outstanding/wave, never drained mid-loop)
        if (pf) {
          gld_lds16(Abase + soff[p] + kn, An + (tid + 512 * p) * 16);
          gld_lds16(Bbase + soff[p] + kn, Bn + (tid + 512 * p) * 16);
        }
        asm volatile("s_barrier" ::: "memory");
      }
      __builtin_amdgcn_s_setprio(1);
      #pragma unroll
      for (int nt = 0; nt < 4; ++nt)
        acc[2 * p + 0][nt] = __builtin_amdgcn_mfma_scale_f32_16x16x128_f8f6f4(
            af0, bf[nt], acc[2 * p + 0][nt],
            0, 0,            // cbsz = fp8(e4m3), blgp = fp8(e4m3)
            0, 127,          // scale A: opsel 0, e8m0 127 = 1.0
            0, 127);         // scale B: 1.0
      #pragma unroll
      for (int nt = 0; nt < 4; ++nt)
        acc[2 * p + 1][nt] = __builtin_amdgcn_mfma_scale_f32_16x16x128_f8f6f4(
            af1, bf[nt], acc[2 * p + 1][nt],
            0, 0, 0, 127, 0, 127);
      __builtin_amdgcn_s_setprio(0);
      asm volatile("s_barrier" ::: "memory");
    }
  }

  // ---- epilogue. C/D layout: col = lane&15, row = (lane>>4)*4 + reg ----
  const int col0 = bx * BN + wn * 64 + rl;
  float hn[4], sc[4];
  #pragma unroll
  for (int nt = 0; nt < 4; ++nt) {
    hn[nt] = hneg[col0 + nt * 16];
    sc[nt] = isc[col0 + nt * 16];
  }
  const int row0 = by * BM + wm * 128 + (q << 2);

  // diag: rows wm*128.. overlap cols wn*64.. iff wm == wn>>1; then
  // row==col selects mt = (wn&1)*4 + nt, lanes q == rl>>2, reg rl&3.
  if (bx == by && wm == (wn >> 1) && q == (rl >> 2)) {
    #pragma unroll
    for (int nt = 0; nt < 4; ++nt) {
      const int mt = (wn & 1) * 4 + nt;
      diag[bx * BN + wn * 64 + nt * 16 + rl] = acc[mt][nt][rl & 3] * sc[nt];
    }
  }

  #pragma unroll
  for (int mt = 0; mt < 8; ++mt) {
    #pragma unroll
    for (int rr = 0; rr < 4; ++rr) {
      float p = 0.f;
      #pragma unroll
      for (int nt = 0; nt < 4; ++nt)
        p += __expf(INV_T * (acc[mt][nt][rr] * sc[nt] - hn[nt]));
      // reduce across 16 cols (lane&15 group)
      p += __shfl_xor(p, 1);
      p += __shfl_xor(p, 2);
      p += __shfl_xor(p, 4);
      p += __shfl_xor(p, 8);
      if (rl == 0)
        atomicAdd(&rowsum[row0 + mt * 16 + rr], p);
    }
  }
}

// ---------------------------------------------------------------------------
// Kernel 3: loss = (1/B) sum_i [ log(rowsum[i]) - INV_T*(diag[i] - hneg[i]) ]
// ---------------------------------------------------------------------------
__global__ __launch_bounds__(256) void finalize_kernel(
    const float* __restrict__ hneg, const float* __restrict__ rowsum,
    const float* __restrict__ diag, float* __restrict__ out)
{
  const int i = blockIdx.x * 256 + threadIdx.x;
  const int lane = threadIdx.x & 63;
  const int wave = threadIdx.x >> 6;

  float c = __logf(rowsum[i]) - INV_T * (diag[i] - hneg[i]);
  #pragma unroll
  for (int off = 32; off >= 1; off >>= 1) c += __shfl_xor(c, off);

  __shared__ float red[4];
  if (lane == 0) red[wave] = c;
  __syncthreads();
  if (threadIdx.x == 0)
    atomicAdd(out, (red[0] + red[1] + red[2] + red[3]) * (1.0f / BATCH));
}

// ---------------------------------------------------------------------------
extern "C" void kernel_launch(void* const* d_in, const int* in_sizes, int n_in,
                              void* d_out, int out_size, void* d_ws, size_t ws_size,
                              hipStream_t stream) {
  const float* ci = (const float*)d_in[0];
  const float* cj = (const float*)d_in[1];
  float* out = (float*)d_out;

  // ws: Li8 u8[B*D] | Qb8 u8[B*D] | hneg f32[B] | isc f32[B] | rowsum f32[B] | diag f32[B]
  unsigned char* Li8 = (unsigned char*)d_ws;
  unsigned char* Qb8 = Li8 + (size_t)BATCH * DIM;
  float* hneg   = (float*)(Qb8 + (size_t)BATCH * DIM);
  float* isc    = hneg + BATCH;
  float* rowsum = isc + BATCH;
  float* diag   = rowsum + BATCH;

  prep_kernel<<<2 * BATCH / 4, 256, 0, stream>>>(ci, cj, Li8, Qb8, hneg, isc, rowsum, out);
  gemm_lse_kernel<<<(BATCH / BM) * (BATCH / BN), 512, 0, stream>>>(Li8, Qb8, hneg, isc, rowsum, diag);
  finalize_kernel<<<BATCH / 256, 256, 0, stream>>>(hneg, rowsum, diag, out);
}

// Round 3
// 144.619 us; speedup vs baseline: 1.1788x; 1.1788x over previous
//
#include <hip/hip_runtime.h>
#include <hip/hip_bf16.h>
#include <math.h>

#define BATCH 4096
#define DIM   2048
#define INV_T 2.0f   // 1 / TEMPERATURE, TEMPERATURE = 0.5

#define BM 256
#define BN 256

typedef float floatx4 __attribute__((ext_vector_type(4)));
typedef int   intx4   __attribute__((ext_vector_type(4)));
typedef int   intx8   __attribute__((ext_vector_type(8)));

static __device__ __forceinline__ void gld_lds16(const void* g, void* l) {
  __builtin_amdgcn_global_load_lds(
      (const __attribute__((address_space(1))) void*)g,
      (__attribute__((address_space(3))) void*)l, 16, 0, 0);
}

static __device__ __forceinline__ intx8 comb8(intx4 lo, intx4 hi) {
  intx8 r;
  r[0] = lo[0]; r[1] = lo[1]; r[2] = lo[2]; r[3] = lo[3];
  r[4] = hi[0]; r[5] = hi[1]; r[6] = hi[2]; r[7] = hi[3];
  return r;
}

// ---------------------------------------------------------------------------
// Kernel 1: per-row log-softmax prep. Wave-per-row, NO barriers. (unchanged)
//   rows [0, B)  -> Li8 = fp8_e4m3(log_softmax(c_i))
//   rows [B, 2B) -> Qb8 = fp8_e4m3(softmax(c_j) * 2^t_j)  (per-row pow2 scale
//                   so max lands ~[128,256): avoids e4m3 underflow)
//                   + hneg fp32 (from EXACT fp32 Q) + isc = 2^-t + rowsum = 0
// ---------------------------------------------------------------------------
__global__ __launch_bounds__(256) void prep_kernel(
    const float* __restrict__ ci, const float* __restrict__ cj,
    unsigned char* __restrict__ Li8, unsigned char* __restrict__ Qb8,
    float* __restrict__ hneg, float* __restrict__ isc,
    float* __restrict__ rowsum, float* __restrict__ out)
{
  const int lane = threadIdx.x & 63;
  const int wave = threadIdx.x >> 6;
  const int row = blockIdx.x * 4 + wave;
  const bool isj = row >= BATCH;
  const int r = isj ? row - BATCH : row;
  const float* __restrict__ src = (isj ? cj : ci) + (size_t)r * DIM;

  // 32 elements per lane: float4 chunks at [i*64 + lane], i = 0..7
  float v[32];
  #pragma unroll
  for (int i = 0; i < 8; ++i) {
    float4 t = ((const float4*)src)[i * 64 + lane];
    v[i * 4 + 0] = t.x; v[i * 4 + 1] = t.y;
    v[i * 4 + 2] = t.z; v[i * 4 + 3] = t.w;
  }

  // wave max
  float m = v[0];
  #pragma unroll
  for (int i = 1; i < 32; ++i) m = fmaxf(m, v[i]);
  #pragma unroll
  for (int off = 32; off >= 1; off >>= 1) m = fmaxf(m, __shfl_xor(m, off));

  // wave sum of exp(v - m)
  float s = 0.f;
  #pragma unroll
  for (int i = 0; i < 32; ++i) s += __expf(v[i] - m);
  #pragma unroll
  for (int off = 32; off >= 1; off >>= 1) s += __shfl_xor(s, off);
  const float ls = m + __logf(s);          // logsumexp of row

  // per-row pow2 scale for Q rows: Qmax = exp(m - ls); want Qmax*2^t in [128,256)
  float scale = 1.f;
  int t = 0;
  if (isj) {
    const float qmax = __expf(m - ls);
    const int be = (int)((__float_as_uint(qmax) >> 23) & 0xff);
    t = 134 - be;                          // qmax*2^t in [128,256)
    scale = __uint_as_float((unsigned)(t + 127) << 23);
  }

  unsigned char* dst = (isj ? Qb8 : Li8) + (size_t)r * DIM;
  float h = 0.f;
  #pragma unroll
  for (int i = 0; i < 8; ++i) {
    float f[4];
    #pragma unroll
    for (int j = 0; j < 4; ++j) {
      const float li = v[i * 4 + j] - ls;  // log_softmax element
      if (isj) {
        const float q = __expf(li);        // exact softmax element
        h += q * li;                       // negative entropy (fp32, exact Q)
        f[j] = q * scale;
      } else {
        f[j] = li;
      }
    }
    int w = __builtin_amdgcn_cvt_pk_fp8_f32(f[0], f[1], 0, false);
    w = __builtin_amdgcn_cvt_pk_fp8_f32(f[2], f[3], w, true);
    ((int*)dst)[i * 64 + lane] = w;        // bytes (i*256 + lane*4) ..+3
  }

  if (isj) {
    #pragma unroll
    for (int off = 32; off >= 1; off >>= 1) h += __shfl_xor(h, off);
    if (lane == 0) {
      hneg[r] = h;
      isc[r] = __uint_as_float((unsigned)(127 - t) << 23);  // 2^-t
      rowsum[r] = 0.f;
    }
  }
  if (row == 0 && lane == 0) out[0] = 0.f;
}

// ---------------------------------------------------------------------------
// Kernel 2 (R8): cross' = Li8 @ Qb8^T via MX-fp8 MFMA (16x16x128, scale=1.0).
// 256^2 tile, 8-wave 4-phase counted-vmcnt schedule (T1+T3+T4+T5).
// R8 fix: R6/R7's diag epilogue indexed acc[(wn&1)*4+nt] with RUNTIME wn
// (rule #20) -> entire acc[8][4] array demoted to scratch -> 200 MB HBM
// write traffic (L2 scratch thrash), VGPR_Count 116, MfmaUtil 16%.
// Diag now uses fully compile-time acc indices; runtime conditions moved
// into the store predicate. Semantics identical (row=wm*128+mt*16+q*4+rr,
// col=wn*64+nt*16+rl; diag <=> mt=(wn&1)*4+nt, q=rl>>2, rr=rl&3).
// ---------------------------------------------------------------------------
__global__ __launch_bounds__(512, 1) void gemm_lse_kernel(
    const unsigned char* __restrict__ Li8, const unsigned char* __restrict__ Qb8,
    const float* __restrict__ hneg, const float* __restrict__ isc,
    float* __restrict__ rowsum, float* __restrict__ diag)
{
  // 2 dbuf x (A 256x128 + B 256x128) fp8 = 128 KB
  __shared__ __attribute__((aligned(16))) unsigned char As_[2][BM * 128];
  __shared__ __attribute__((aligned(16))) unsigned char Bs_[2][BN * 128];

  const int tid  = threadIdx.x;
  // XCD-aware patch mapping: 256 blocks, xcd = lin&7 owns a 4(by) x 8(bx)
  // rectangle of the 16x16 tile grid (bijective).
  const int lin = blockIdx.x;
  const int xc  = lin & 7;
  const int sq  = lin >> 3;                // 0..31
  const int by  = (xc & 3) * 4 + (sq & 3);
  const int bx  = (xc >> 2) * 8 + (sq >> 2);

  const int lane = tid & 63;
  const int wave = tid >> 6;               // 0..7
  const int wm   = wave >> 2;              // 0..1 -> row band wm*128
  const int wn   = wave & 3;               // 0..3 -> col band wn*64

  // staging: 2048 16B-chunks per operand-tile; thread t does chunks t+512*s.
  // LDS chunk p holds global chunk (row = p>>3, cb = (p&7) ^ (row&7)).
  int soff[4];
  #pragma unroll
  for (int s = 0; s < 4; ++s) {
    const int p = tid + 512 * s;
    const int row = p >> 3;
    const int cbg = (p & 7) ^ (row & 7);
    soff[s] = row * DIM + cbg * 16;
  }
  const unsigned char* Abase = Li8 + (size_t)(by * BM) * DIM;
  const unsigned char* Bbase = Qb8 + (size_t)(bx * BN) * DIM;

  const int rl = lane & 15;                // m/n within frag; col within C/D
  const int q  = lane >> 4;                // k-quad: k in [q*32, q*32+32)
  const int sw = rl & 7;                   // XOR swizzle key (row & 7)

  floatx4 acc[8][4];
  const floatx4 z = {0.f, 0.f, 0.f, 0.f};
  #pragma unroll
  for (int mt = 0; mt < 8; ++mt)
    #pragma unroll
    for (int nt = 0; nt < 4; ++nt) acc[mt][nt] = z;

  // prologue: stage K-tile 0 into buffer 0 (8 loads/thread)
  #pragma unroll
  for (int s = 0; s < 4; ++s) {
    gld_lds16(Abase + soff[s], &As_[0][0] + (tid + 512 * s) * 16);
    gld_lds16(Bbase + soff[s], &Bs_[0][0] + (tid + 512 * s) * 16);
  }

  for (int t = 0; t < 16; ++t) {
    const unsigned char* Ab = &As_[t & 1][0];
    const unsigned char* Bb = &Bs_[t & 1][0];
    unsigned char* An = &As_[(t & 1) ^ 1][0];
    unsigned char* Bn = &Bs_[(t & 1) ^ 1][0];
    const int kn = (t + 1) * 128;
    const bool pf = (t < 15);

    intx8 bf[4];

    #pragma unroll
    for (int p = 0; p < 4; ++p) {
      if (p == 0) {
        // boundary: issue first staging pair for t+1, then counted wait for
        // ALL of tile t's loads (2 newest stay in flight), then barrier so
        // every wave's staging of tile t is known-landed chip-wide.
        if (pf) {
          gld_lds16(Abase + soff[0] + kn, An + tid * 16);
          gld_lds16(Bbase + soff[0] + kn, Bn + tid * 16);
          asm volatile("s_waitcnt vmcnt(2)" ::: "memory");
        } else {
          asm volatile("s_waitcnt vmcnt(0)" ::: "memory");
        }
        asm volatile("s_barrier" ::: "memory");
        // B fragments for the whole K-tile (held across phases, 32 VGPRs)
        #pragma unroll
        for (int nt = 0; nt < 4; ++nt) {
          const int rb = wn * 64 + nt * 16 + rl;
          const int q0 = rb * 8 + ((2 * q) ^ sw);
          const int q1 = rb * 8 + ((2 * q + 1) ^ sw);
          bf[nt] = comb8(*(const intx4*)(Bb + q0 * 16),
                         *(const intx4*)(Bb + q1 * 16));
        }
      }
      // A fragments for this phase's mt pair (issued before the barrier for
      // phases 1-3 so the ds_read latency hides under other waves' MFMA)
      intx8 af0, af1;
      {
        const int ra0 = wm * 128 + (2 * p) * 16 + rl;
        const int a00 = ra0 * 8 + ((2 * q) ^ sw);
        const int a01 = ra0 * 8 + ((2 * q + 1) ^ sw);
        af0 = comb8(*(const intx4*)(Ab + a00 * 16),
                    *(const intx4*)(Ab + a01 * 16));
        const int ra1 = wm * 128 + (2 * p + 1) * 16 + rl;
        const int a10 = ra1 * 8 + ((2 * q) ^ sw);
        const int a11 = ra1 * 8 + ((2 * q + 1) ^ sw);
        af1 = comb8(*(const intx4*)(Ab + a10 * 16),
                    *(const intx4*)(Ab + a11 * 16));
      }
      if (p != 0) {
        // spread staging: one A/B pair per phase (keeps loads in flight
        // across barriers; max ~10 outstanding/wave, never drained mid-loop)
        if (pf) {
          gld_lds16(Abase + soff[p] + kn, An + (tid + 512 * p) * 16);
          gld_lds16(Bbase + soff[p] + kn, Bn + (tid + 512 * p) * 16);
        }
        asm volatile("s_barrier" ::: "memory");
      }
      __builtin_amdgcn_s_setprio(1);
      #pragma unroll
      for (int nt = 0; nt < 4; ++nt)
        acc[2 * p + 0][nt] = __builtin_amdgcn_mfma_scale_f32_16x16x128_f8f6f4(
            af0, bf[nt], acc[2 * p + 0][nt],
            0, 0,            // cbsz = fp8(e4m3), blgp = fp8(e4m3)
            0, 127,          // scale A: opsel 0, e8m0 127 = 1.0
            0, 127);         // scale B: 1.0
      #pragma unroll
      for (int nt = 0; nt < 4; ++nt)
        acc[2 * p + 1][nt] = __builtin_amdgcn_mfma_scale_f32_16x16x128_f8f6f4(
            af1, bf[nt], acc[2 * p + 1][nt],
            0, 0, 0, 127, 0, 127);
      __builtin_amdgcn_s_setprio(0);
      asm volatile("s_barrier" ::: "memory");
    }
  }

  // ---- epilogue. C/D layout: col = lane&15, row = (lane>>4)*4 + reg ----
  const int col0 = bx * BN + wn * 64 + rl;
  float hn[4], sc[4];
  #pragma unroll
  for (int nt = 0; nt < 4; ++nt) {
    hn[nt] = hneg[col0 + nt * 16];
    sc[nt] = isc[col0 + nt * 16];
  }
  const int row0 = by * BM + wm * 128 + (q << 2);

  // diag: rows wm*128.. overlap cols wn*64.. iff wm == wn>>1; row==col picks
  // mt = (wn&1)*4 + nt, q == rl>>2, reg rr == rl&3. ALL acc indices below are
  // compile-time (rule #20: runtime-indexed reg arrays demote to scratch);
  // the runtime selection lives in the store predicate instead.
  if (bx == by && wm == (wn >> 1) && q == (rl >> 2)) {
    #pragma unroll
    for (int half = 0; half < 2; ++half) {
      #pragma unroll
      for (int nt = 0; nt < 4; ++nt) {
        #pragma unroll
        for (int rr = 0; rr < 4; ++rr) {
          if ((wn & 1) == half && (rl & 3) == rr)
            diag[bx * BN + wn * 64 + nt * 16 + rl] =
                acc[half * 4 + nt][nt][rr] * sc[nt];
        }
      }
    }
  }

  #pragma unroll
  for (int mt = 0; mt < 8; ++mt) {
    #pragma unroll
    for (int rr = 0; rr < 4; ++rr) {
      float p = 0.f;
      #pragma unroll
      for (int nt = 0; nt < 4; ++nt)
        p += __expf(INV_T * (acc[mt][nt][rr] * sc[nt] - hn[nt]));
      // reduce across 16 cols (lane&15 group)
      p += __shfl_xor(p, 1);
      p += __shfl_xor(p, 2);
      p += __shfl_xor(p, 4);
      p += __shfl_xor(p, 8);
      if (rl == 0)
        atomicAdd(&rowsum[row0 + mt * 16 + rr], p);
    }
  }
}

// ---------------------------------------------------------------------------
// Kernel 3: loss = (1/B) sum_i [ log(rowsum[i]) - INV_T*(diag[i] - hneg[i]) ]
// ---------------------------------------------------------------------------
__global__ __launch_bounds__(256) void finalize_kernel(
    const float* __restrict__ hneg, const float* __restrict__ rowsum,
    const float* __restrict__ diag, float* __restrict__ out)
{
  const int i = blockIdx.x * 256 + threadIdx.x;
  const int lane = threadIdx.x & 63;
  const int wave = threadIdx.x >> 6;

  float c = __logf(rowsum[i]) - INV_T * (diag[i] - hneg[i]);
  #pragma unroll
  for (int off = 32; off >= 1; off >>= 1) c += __shfl_xor(c, off);

  __shared__ float red[4];
  if (lane == 0) red[wave] = c;
  __syncthreads();
  if (threadIdx.x == 0)
    atomicAdd(out, (red[0] + red[1] + red[2] + red[3]) * (1.0f / BATCH));
}

// ---------------------------------------------------------------------------
extern "C" void kernel_launch(void* const* d_in, const int* in_sizes, int n_in,
                              void* d_out, int out_size, void* d_ws, size_t ws_size,
                              hipStream_t stream) {
  const float* ci = (const float*)d_in[0];
  const float* cj = (const float*)d_in[1];
  float* out = (float*)d_out;

  // ws: Li8 u8[B*D] | Qb8 u8[B*D] | hneg f32[B] | isc f32[B] | rowsum f32[B] | diag f32[B]
  unsigned char* Li8 = (unsigned char*)d_ws;
  unsigned char* Qb8 = Li8 + (size_t)BATCH * DIM;
  float* hneg   = (float*)(Qb8 + (size_t)BATCH * DIM);
  float* isc    = hneg + BATCH;
  float* rowsum = isc + BATCH;
  float* diag   = rowsum + BATCH;

  prep_kernel<<<2 * BATCH / 4, 256, 0, stream>>>(ci, cj, Li8, Qb8, hneg, isc, rowsum, out);
  gemm_lse_kernel<<<(BATCH / BM) * (BATCH / BN), 512, 0, stream>>>(Li8, Qb8, hneg, isc, rowsum, diag);
  finalize_kernel<<<BATCH / 256, 256, 0, stream>>>(hneg, rowsum, diag, out);
}

// Round 4
// 142.804 us; speedup vs baseline: 1.1937x; 1.0127x over previous
//
#include <hip/hip_runtime.h>
#include <hip/hip_bf16.h>
#include <math.h>

#define BATCH 4096
#define DIM   2048
#define INV_T 2.0f   // 1 / TEMPERATURE, TEMPERATURE = 0.5

#define BM 256
#define BN 256

typedef float floatx4 __attribute__((ext_vector_type(4)));
typedef int   intx4   __attribute__((ext_vector_type(4)));
typedef int   intx8   __attribute__((ext_vector_type(8)));

static __device__ __forceinline__ void gld_lds16(const void* g, void* l) {
  __builtin_amdgcn_global_load_lds(
      (const __attribute__((address_space(1))) void*)g,
      (__attribute__((address_space(3))) void*)l, 16, 0, 0);
}

static __device__ __forceinline__ intx8 comb8(intx4 lo, intx4 hi) {
  intx8 r;
  r[0] = lo[0]; r[1] = lo[1]; r[2] = lo[2]; r[3] = lo[3];
  r[4] = hi[0]; r[5] = hi[1]; r[6] = hi[2]; r[7] = hi[3];
  return r;
}

// ---------------------------------------------------------------------------
// Kernel 1: per-row log-softmax prep. Wave-per-row, NO barriers. (unchanged)
// ---------------------------------------------------------------------------
__global__ __launch_bounds__(256) void prep_kernel(
    const float* __restrict__ ci, const float* __restrict__ cj,
    unsigned char* __restrict__ Li8, unsigned char* __restrict__ Qb8,
    float* __restrict__ hneg, float* __restrict__ isc,
    float* __restrict__ rowsum, float* __restrict__ out)
{
  const int lane = threadIdx.x & 63;
  const int wave = threadIdx.x >> 6;
  const int row = blockIdx.x * 4 + wave;
  const bool isj = row >= BATCH;
  const int r = isj ? row - BATCH : row;
  const float* __restrict__ src = (isj ? cj : ci) + (size_t)r * DIM;

  // 32 elements per lane: float4 chunks at [i*64 + lane], i = 0..7
  float v[32];
  #pragma unroll
  for (int i = 0; i < 8; ++i) {
    float4 t = ((const float4*)src)[i * 64 + lane];
    v[i * 4 + 0] = t.x; v[i * 4 + 1] = t.y;
    v[i * 4 + 2] = t.z; v[i * 4 + 3] = t.w;
  }

  // wave max
  float m = v[0];
  #pragma unroll
  for (int i = 1; i < 32; ++i) m = fmaxf(m, v[i]);
  #pragma unroll
  for (int off = 32; off >= 1; off >>= 1) m = fmaxf(m, __shfl_xor(m, off));

  // wave sum of exp(v - m)
  float s = 0.f;
  #pragma unroll
  for (int i = 0; i < 32; ++i) s += __expf(v[i] - m);
  #pragma unroll
  for (int off = 32; off >= 1; off >>= 1) s += __shfl_xor(s, off);
  const float ls = m + __logf(s);          // logsumexp of row

  // per-row pow2 scale for Q rows: Qmax = exp(m - ls); want Qmax*2^t in [128,256)
  float scale = 1.f;
  int t = 0;
  if (isj) {
    const float qmax = __expf(m - ls);
    const int be = (int)((__float_as_uint(qmax) >> 23) & 0xff);
    t = 134 - be;                          // qmax*2^t in [128,256)
    scale = __uint_as_float((unsigned)(t + 127) << 23);
  }

  unsigned char* dst = (isj ? Qb8 : Li8) + (size_t)r * DIM;
  float h = 0.f;
  #pragma unroll
  for (int i = 0; i < 8; ++i) {
    float f[4];
    #pragma unroll
    for (int j = 0; j < 4; ++j) {
      const float li = v[i * 4 + j] - ls;  // log_softmax element
      if (isj) {
        const float q = __expf(li);        // exact softmax element
        h += q * li;                       // negative entropy (fp32, exact Q)
        f[j] = q * scale;
      } else {
        f[j] = li;
      }
    }
    int w = __builtin_amdgcn_cvt_pk_fp8_f32(f[0], f[1], 0, false);
    w = __builtin_amdgcn_cvt_pk_fp8_f32(f[2], f[3], w, true);
    ((int*)dst)[i * 64 + lane] = w;        // bytes (i*256 + lane*4) ..+3
  }

  if (isj) {
    #pragma unroll
    for (int off = 32; off >= 1; off >>= 1) h += __shfl_xor(h, off);
    if (lane == 0) {
      hneg[r] = h;
      isc[r] = __uint_as_float((unsigned)(127 - t) << 23);  // 2^-t
      rowsum[r] = 0.f;
    }
  }
  if (row == 0 && lane == 0) out[0] = 0.f;
}

// ---------------------------------------------------------------------------
// Kernel 2 (R9): cross' = Li8 @ Qb8^T via MX-fp8 MFMA (16x16x128, scale=1.0).
// R9 restructure: R8's 8-barrier-per-K-tile phase lockstep made LDS reads and
// MFMA run SERIALLY (measured ~8000 cy/K-tile vs MFMA 2211 + LDS 3100; MfmaUtil
// 23%). Now: 2 barriers per K-tile (dbuf minimum), counted vmcnt(8) at the
// tile boundary only (T4 - never drain mid-loop), and per-frag register
// pipelining inside the tile: af[s+1]'s 2 ds_reads are issued before the
// 4-MFMA cluster consuming af[s], so LDS-read time hides under MFMA and
// free-running waves interleave (T5 setprio now has role diversity).
// Register-neutral: af ping-pong (16) replaces the old af0/af1 pair (16);
// total ~220 <= 256-reg class (8 waves/CU, no spill).
// ---------------------------------------------------------------------------
__global__ __launch_bounds__(512, 1) void gemm_lse_kernel(
    const unsigned char* __restrict__ Li8, const unsigned char* __restrict__ Qb8,
    const float* __restrict__ hneg, const float* __restrict__ isc,
    float* __restrict__ rowsum, float* __restrict__ diag)
{
  // 2 dbuf x (A 256x128 + B 256x128) fp8 = 128 KB
  __shared__ __attribute__((aligned(16))) unsigned char As_[2][BM * 128];
  __shared__ __attribute__((aligned(16))) unsigned char Bs_[2][BN * 128];

  const int tid  = threadIdx.x;
  // XCD-aware patch mapping: 256 blocks, xcd = lin&7 owns a 4(by) x 8(bx)
  // rectangle of the 16x16 tile grid (bijective).
  const int lin = blockIdx.x;
  const int xc  = lin & 7;
  const int sq  = lin >> 3;                // 0..31
  const int by  = (xc & 3) * 4 + (sq & 3);
  const int bx  = (xc >> 2) * 8 + (sq >> 2);

  const int lane = tid & 63;
  const int wave = tid >> 6;               // 0..7
  const int wm   = wave >> 2;              // 0..1 -> row band wm*128
  const int wn   = wave & 3;               // 0..3 -> col band wn*64

  // staging: 2048 16B-chunks per operand-tile; thread t does chunks t+512*s.
  // LDS chunk p holds global chunk (row = p>>3, cb = (p&7) ^ (row&7)).
  int soff[4];
  #pragma unroll
  for (int s = 0; s < 4; ++s) {
    const int p = tid + 512 * s;
    const int row = p >> 3;
    const int cbg = (p & 7) ^ (row & 7);
    soff[s] = row * DIM + cbg * 16;
  }
  const unsigned char* Abase = Li8 + (size_t)(by * BM) * DIM;
  const unsigned char* Bbase = Qb8 + (size_t)(bx * BN) * DIM;

  const int rl = lane & 15;                // m/n within frag; col within C/D
  const int q  = lane >> 4;                // k-quad: k in [q*32, q*32+32)
  const int sw = rl & 7;                   // XOR swizzle key (row & 7)

  floatx4 acc[8][4];
  const floatx4 z = {0.f, 0.f, 0.f, 0.f};
  #pragma unroll
  for (int mt = 0; mt < 8; ++mt)
    #pragma unroll
    for (int nt = 0; nt < 4; ++nt) acc[mt][nt] = z;

  // prologue: stage K-tile 0 into buffer 0 (8 loads/thread)
  #pragma unroll
  for (int s = 0; s < 4; ++s) {
    gld_lds16(Abase + soff[s], &As_[0][0] + (tid + 512 * s) * 16);
    gld_lds16(Bbase + soff[s], &Bs_[0][0] + (tid + 512 * s) * 16);
  }

  for (int t = 0; t < 16; ++t) {
    const int cur = t & 1;
    const unsigned char* Ab = &As_[cur][0];
    const unsigned char* Bb = &Bs_[cur][0];
    unsigned char* An = &As_[cur ^ 1][0];
    unsigned char* Bn = &Bs_[cur ^ 1][0];
    const int kn = (t + 1) * 128;

    // issue ALL of next tile's staging up front (8 loads; they drain over the
    // whole ~3000-cy tile), then counted wait: vmcnt(8) = everything from
    // tile t has landed, t+1's 8 stay in flight across the barrier.
    if (t < 15) {
      #pragma unroll
      for (int s = 0; s < 4; ++s) {
        gld_lds16(Abase + soff[s] + kn, An + (tid + 512 * s) * 16);
        gld_lds16(Bbase + soff[s] + kn, Bn + (tid + 512 * s) * 16);
      }
      asm volatile("s_waitcnt vmcnt(8)" ::: "memory");
    } else {
      asm volatile("s_waitcnt vmcnt(0)" ::: "memory");
    }
    asm volatile("s_barrier" ::: "memory");

    // ---- compute on buf[cur]: no barriers inside the tile ----
    // B fragments for the whole K-tile (32 VGPRs)
    intx8 bf[4];
    #pragma unroll
    for (int nt = 0; nt < 4; ++nt) {
      const int rb = wn * 64 + nt * 16 + rl;
      const int q0 = rb * 8 + ((2 * q) ^ sw);
      const int q1 = rb * 8 + ((2 * q + 1) ^ sw);
      bf[nt] = comb8(*(const intx4*)(Bb + q0 * 16),
                     *(const intx4*)(Bb + q1 * 16));
    }
    // A-fragment ping-pong, pipelined one sub-step ahead (af[s+1] reads
    // issue before the MFMA cluster on af[s]; compiler emits the partial
    // lgkmcnt). All indices compile-time after unroll (rule #20).
    intx8 af[2];
    {
      const int ra = wm * 128 + rl;
      const int a0 = ra * 8 + ((2 * q) ^ sw);
      const int a1 = ra * 8 + ((2 * q + 1) ^ sw);
      af[0] = comb8(*(const intx4*)(Ab + a0 * 16),
                    *(const intx4*)(Ab + a1 * 16));
    }
    #pragma unroll
    for (int s = 0; s < 8; ++s) {
      if (s < 7) {
        const int ra = wm * 128 + (s + 1) * 16 + rl;
        const int a0 = ra * 8 + ((2 * q) ^ sw);
        const int a1 = ra * 8 + ((2 * q + 1) ^ sw);
        af[(s + 1) & 1] = comb8(*(const intx4*)(Ab + a0 * 16),
                                *(const intx4*)(Ab + a1 * 16));
      }
      __builtin_amdgcn_s_setprio(1);
      #pragma unroll
      for (int nt = 0; nt < 4; ++nt)
        acc[s][nt] = __builtin_amdgcn_mfma_scale_f32_16x16x128_f8f6f4(
            af[s & 1], bf[nt], acc[s][nt],
            0, 0,            // cbsz = fp8(e4m3), blgp = fp8(e4m3)
            0, 127,          // scale A: opsel 0, e8m0 127 = 1.0
            0, 127);         // scale B: 1.0
      __builtin_amdgcn_s_setprio(0);
    }

    // end barrier: all waves done READING buf[cur] before iteration t+1
    // stages tile t+2 into it.
    asm volatile("s_barrier" ::: "memory");
  }

  // ---- epilogue. C/D layout: col = lane&15, row = (lane>>4)*4 + reg ----
  const int col0 = bx * BN + wn * 64 + rl;
  float hn[4], sc[4];
  #pragma unroll
  for (int nt = 0; nt < 4; ++nt) {
    hn[nt] = hneg[col0 + nt * 16];
    sc[nt] = isc[col0 + nt * 16];
  }
  const int row0 = by * BM + wm * 128 + (q << 2);

  // diag: rows wm*128.. overlap cols wn*64.. iff wm == wn>>1; row==col picks
  // mt = (wn&1)*4 + nt, q == rl>>2, reg rr == rl&3. ALL acc indices below are
  // compile-time (rule #20); runtime selection lives in the store predicate.
  if (bx == by && wm == (wn >> 1) && q == (rl >> 2)) {
    #pragma unroll
    for (int half = 0; half < 2; ++half) {
      #pragma unroll
      for (int nt = 0; nt < 4; ++nt) {
        #pragma unroll
        for (int rr = 0; rr < 4; ++rr) {
          if ((wn & 1) == half && (rl & 3) == rr)
            diag[bx * BN + wn * 64 + nt * 16 + rl] =
                acc[half * 4 + nt][nt][rr] * sc[nt];
        }
      }
    }
  }

  #pragma unroll
  for (int mt = 0; mt < 8; ++mt) {
    #pragma unroll
    for (int rr = 0; rr < 4; ++rr) {
      float p = 0.f;
      #pragma unroll
      for (int nt = 0; nt < 4; ++nt)
        p += __expf(INV_T * (acc[mt][nt][rr] * sc[nt] - hn[nt]));
      // reduce across 16 cols (lane&15 group)
      p += __shfl_xor(p, 1);
      p += __shfl_xor(p, 2);
      p += __shfl_xor(p, 4);
      p += __shfl_xor(p, 8);
      if (rl == 0)
        atomicAdd(&rowsum[row0 + mt * 16 + rr], p);
    }
  }
}

// ---------------------------------------------------------------------------
// Kernel 3: loss = (1/B) sum_i [ log(rowsum[i]) - INV_T*(diag[i] - hneg[i]) ]
// ---------------------------------------------------------------------------
__global__ __launch_bounds__(256) void finalize_kernel(
    const float* __restrict__ hneg, const float* __restrict__ rowsum,
    const float* __restrict__ diag, float* __restrict__ out)
{
  const int i = blockIdx.x * 256 + threadIdx.x;
  const int lane = threadIdx.x & 63;
  const int wave = threadIdx.x >> 6;

  float c = __logf(rowsum[i]) - INV_T * (diag[i] - hneg[i]);
  #pragma unroll
  for (int off = 32; off >= 1; off >>= 1) c += __shfl_xor(c, off);

  __shared__ float red[4];
  if (lane == 0) red[wave] = c;
  __syncthreads();
  if (threadIdx.x == 0)
    atomicAdd(out, (red[0] + red[1] + red[2] + red[3]) * (1.0f / BATCH));
}

// ---------------------------------------------------------------------------
extern "C" void kernel_launch(void* const* d_in, const int* in_sizes, int n_in,
                              void* d_out, int out_size, void* d_ws, size_t ws_size,
                              hipStream_t stream) {
  const float* ci = (const float*)d_in[0];
  const float* cj = (const float*)d_in[1];
  float* out = (float*)d_out;

  // ws: Li8 u8[B*D] | Qb8 u8[B*D] | hneg f32[B] | isc f32[B] | rowsum f32[B] | diag f32[B]
  unsigned char* Li8 = (unsigned char*)d_ws;
  unsigned char* Qb8 = Li8 + (size_t)BATCH * DIM;
  float* hneg   = (float*)(Qb8 + (size_t)BATCH * DIM);
  float* isc    = hneg + BATCH;
  float* rowsum = isc + BATCH;
  float* diag   = rowsum + BATCH;

  prep_kernel<<<2 * BATCH / 4, 256, 0, stream>>>(ci, cj, Li8, Qb8, hneg, isc, rowsum, out);
  gemm_lse_kernel<<<(BATCH / BM) * (BATCH / BN), 512, 0, stream>>>(Li8, Qb8, hneg, isc, rowsum, diag);
  finalize_kernel<<<BATCH / 256, 256, 0, stream>>>(hneg, rowsum, diag, out);
}